// Round 9
// baseline (1459.659 us; speedup 1.0000x reference)
//
#include <hip/hip_runtime.h>
#include <hip/hip_bf16.h>
#include <hip/hip_cooperative_groups.h>

namespace cg = cooperative_groups;

#define NNODES 50000
#define NEDGES 800000
#define NTILE_N 782       // ceil(NNODES/64)
#define TRN_ITEMS 114688  // 5 weight transposes
#define ZWORDS4 1650012   // (N*131 + 50048)/4

typedef short bf16x8 __attribute__((ext_vector_type(8)));
typedef float f32x4 __attribute__((ext_vector_type(4)));
typedef unsigned short u16;
typedef unsigned int u32;

__device__ __forceinline__ u16 f2bf(float f) {
    __hip_bfloat16 b = __float2bfloat16(f);
    return *reinterpret_cast<u16*>(&b);
}
__device__ __forceinline__ float bf2f(u16 v) {
    u32 u = ((u32)v) << 16;
    return __uint_as_float(u);
}
__device__ __forceinline__ u32 pack2(float a, float b) {
    __hip_bfloat162 t = __float22bfloat162_rn(float2{a, b});
    return *reinterpret_cast<u32*>(&t);
}
__device__ __forceinline__ float fast_silu(float x) {
    float e = __builtin_amdgcn_exp2f(-1.442695040888963f * x);
    return x * __builtin_amdgcn_rcpf(1.0f + e);
}
__device__ __forceinline__ bf16x8 ld8(const u16* p) {
    return *(const bf16x8*)p;
}
__device__ __forceinline__ f32x4 mfma16(bf16x8 a, bf16x8 b, f32x4 c) {
    return __builtin_amdgcn_mfma_f32_16x16x32_bf16(a, b, c, 0, 0, 0);
}

struct MegaParams {
    const float *h, *pos;
    const int *snd, *rcv;
    const float *eW1, *eb1, *eW2, *eb2, *nW1, *nb1, *nW2, *nb2, *pW1, *pb1, *pW2;
    float *agg, *posacc;
    int *counts, *excl, *blkSum, *blkOff, *perm;
    u16 *P, *eW1T, *eW2T, *pW1T, *nW1T, *nW2T;
    float *out;
};

struct __align__(16) EdgeLds {
    u16   m1[64 * 136];
    u16   msg[64 * 136];
    float diff[64][4];
    float pcpart[4][64];
    float wlast[128];
    float radial[64];
    int   sndloc[64];
    int   rcvloc[64];
};

union SharedU {
    EdgeLds edge;
    int     scan[256];
    u16     nm1[64 * 136];
};

// Phases: 1 zero+transpose | 2 hist+gemm_p | 3 scan1 | 4 scan2 | 5 scatter | 6 edge | 7 node+pos
__global__ __launch_bounds__(256, 4) void mega(MegaParams p, int plo, int phi) {
    __shared__ SharedU U;
    const int tid  = threadIdx.x;
    const int gid  = blockIdx.x * 256 + tid;
    const int gsz  = gridDim.x * 256;
    const int w    = tid >> 6;
    const int lane = tid & 63;
    const int m    = lane & 15;
    const int quad = lane >> 4;
    const int ksub = quad * 8;

    for (int ph = plo; ph <= phi; ph++) {
        if (ph == 1) {
            f32x4* z = (f32x4*)p.agg;
            for (int i = gid; i < ZWORDS4; i += gsz) z[i] = (f32x4){0,0,0,0};
            for (int i = gid; i < TRN_ITEMS; i += gsz) {
                int j = i, n, k;
                const float* src; u16* dst;
                if (i < 32768)       { src = p.eW1; dst = p.eW1T; n = j >> 8; k = j & 255; }
                else if (i < 49152)  { j -= 32768; src = p.eW2; dst = p.eW2T; n = j >> 7; k = j & 127; }
                else if (i < 65536)  { j -= 49152; src = p.pW1; dst = p.pW1T; n = j >> 7; k = j & 127; }
                else if (i < 98304)  { j -= 65536; src = p.nW1; dst = p.nW1T; n = j >> 8; k = j & 255; }
                else                 { j -= 98304; src = p.nW2; dst = p.nW2T; n = j >> 7; k = j & 127; }
                dst[j] = f2bf(src[k * 128 + n]);
            }
        } else if (ph == 2) {
            for (int e = gid; e < NEDGES; e += gsz)
                atomicAdd(&p.counts[p.rcv[e]], 1);
            for (int it = blockIdx.x; it < NTILE_N; it += gridDim.x) {
                const int base = it * 64;
                #pragma unroll
                for (int half = 0; half < 2; half++) {
                    bf16x8 bw[4][3];
                    float bias[3];
                    #pragma unroll
                    for (int cc = 0; cc < 3; cc++) {
                        int C = 96 * w + 48 * half + 16 * cc + m;
                        const u16* bp;
                        if (C < 128)      { bp = p.eW1T + C * 256;               bias[cc] = 0.5f * p.eb1[C]; }
                        else if (C < 256) { bp = p.eW1T + (C - 128) * 256 + 128; bias[cc] = 0.5f * p.eb1[C - 128]; }
                        else              { bp = p.nW1T + (C - 256) * 256;       bias[cc] = 0.f; }
                        #pragma unroll
                        for (int t = 0; t < 4; t++) bw[t][cc] = ld8(bp + t * 32 + ksub);
                    }
                    #pragma unroll
                    for (int mt = 0; mt < 4; mt++) {
                        int nm = base + mt * 16 + m;
                        if (nm >= NNODES) nm = NNODES - 1;
                        bf16x8 afr[4];
                        #pragma unroll
                        for (int t = 0; t < 4; t++) {
                            const float* ap = p.h + (size_t)nm * 128 + t * 32 + ksub;
                            f32x4 lo = *(const f32x4*)ap;
                            f32x4 hi = *(const f32x4*)(ap + 4);
                            #pragma unroll
                            for (int j = 0; j < 4; j++) {
                                afr[t][j]     = (short)f2bf(lo[j]);
                                afr[t][4 + j] = (short)f2bf(hi[j]);
                            }
                        }
                        f32x4 acc[3];
                        #pragma unroll
                        for (int cc = 0; cc < 3; cc++) acc[cc] = (f32x4){0,0,0,0};
                        #pragma unroll
                        for (int t = 0; t < 4; t++)
                            #pragma unroll
                            for (int cc = 0; cc < 3; cc++)
                                acc[cc] = mfma16(afr[t], bw[t][cc], acc[cc]);
                        #pragma unroll
                        for (int cc = 0; cc < 3; cc++) {
                            int C = 96 * w + 48 * half + 16 * cc + m;
                            #pragma unroll
                            for (int r = 0; r < 4; r++) {
                                int nr = base + mt * 16 + quad * 4 + r;
                                if (nr < NNODES) p.P[(size_t)nr * 384 + C] = f2bf(acc[cc][r] + bias[cc]);
                            }
                        }
                    }
                }
            }
        } else if (ph == 3) {
            for (int b = blockIdx.x; b < 196; b += gridDim.x) {
                __syncthreads();
                int i = b * 256 + tid;
                int v = (i < NNODES) ? p.counts[i] : 0;
                U.scan[tid] = v;
                __syncthreads();
                for (int off = 1; off < 256; off <<= 1) {
                    int t = (tid >= off) ? U.scan[tid - off] : 0;
                    __syncthreads();
                    U.scan[tid] += t;
                    __syncthreads();
                }
                if (i < NNODES) p.excl[i] = U.scan[tid] - v;
                if (tid == 255) p.blkSum[b] = U.scan[255];
            }
        } else if (ph == 4) {
            if (blockIdx.x == 0) {
                int v = (tid < 196) ? p.blkSum[tid] : 0;
                U.scan[tid] = v;
                __syncthreads();
                for (int off = 1; off < 256; off <<= 1) {
                    int t = (tid >= off) ? U.scan[tid - off] : 0;
                    __syncthreads();
                    U.scan[tid] += t;
                    __syncthreads();
                }
                if (tid < 196) p.blkOff[tid] = U.scan[tid] - v;
            }
        } else if (ph == 5) {
            for (int e = gid; e < NEDGES; e += gsz) {
                int r = p.rcv[e];
                int pi = atomicAdd(&p.excl[r], 1) + p.blkOff[r >> 8];
                p.perm[pi] = e;
            }
        } else if (ph == 6) {
            EdgeLds& S = U.edge;
            const float* eW1last = p.eW1 + 256 * 128;
            bf16x8 bw2[4][2], bp1[4][2];
            float b2v[2], pb1v[2], pw2v[2];
            #pragma unroll
            for (int cc = 0; cc < 2; cc++) {
                int col = (2 * w + cc) * 16 + m;
                #pragma unroll
                for (int t = 0; t < 4; t++) {
                    bw2[t][cc] = ld8(p.eW2T + col * 128 + t * 32 + ksub);
                    bp1[t][cc] = ld8(p.pW1T + col * 128 + t * 32 + ksub);
                }
                b2v[cc]  = p.eb2[col];
                pb1v[cc] = p.pb1[col];
                pw2v[cc] = p.pW2[col];
            }
            if (tid < 128) S.wlast[tid] = eW1last[tid];

            for (int base = blockIdx.x * 64; base < NEDGES; base += gridDim.x * 64) {
                __syncthreads();
                const int e = lane;
                int eg = p.perm[base + e];
                int s = p.snd[eg], r = p.rcv[eg];
                if (tid < 64) {
                    S.sndloc[tid] = s; S.rcvloc[tid] = r;
                    float rad = 0.f;
                    #pragma unroll
                    for (int c = 0; c < 3; c++) {
                        float d = p.pos[s * 3 + c] - p.pos[r * 3 + c];
                        S.diff[tid][c] = d;
                        rad += d * d;
                    }
                    S.radial[tid] = rad;
                }
                __syncthreads();
                {
                    float rad = S.radial[e];
                    const u16* pa = p.P + (size_t)s * 384 + w * 32;
                    const u16* pb = p.P + (size_t)r * 384 + 128 + w * 32;
                    const int sw = e >> 3;
                    #pragma unroll
                    for (int k = 0; k < 4; k++) {
                        bf16x8 va = ld8(pa + k * 8);
                        bf16x8 vb = ld8(pb + k * 8);
                        u32 pk[4];
                        #pragma unroll
                        for (int jj = 0; jj < 4; jj++) {
                            int col = w * 32 + k * 8 + jj * 2;
                            float2 wl = *(const float2*)&S.wlast[col];
                            float v0 = bf2f((u16)va[jj * 2])     + bf2f((u16)vb[jj * 2])     + rad * wl.x;
                            float v1 = bf2f((u16)va[jj * 2 + 1]) + bf2f((u16)vb[jj * 2 + 1]) + rad * wl.y;
                            pk[jj] = pack2(fast_silu(v0), fast_silu(v1));
                        }
                        int chunk = (w * 4 + k) ^ sw;
                        *(uint4*)&S.m1[e * 136 + chunk * 8] =
                            make_uint4(pk[0], pk[1], pk[2], pk[3]);
                    }
                }
                __syncthreads();
                #pragma unroll
                for (int mt = 0; mt < 4; mt++) {
                    const int rs = mt * 2 + (m >> 3);
                    const int row = mt * 16 + m;
                    f32x4 acc0 = (f32x4){0,0,0,0}, acc1 = (f32x4){0,0,0,0};
                    #pragma unroll
                    for (int t = 0; t < 4; t++) {
                        bf16x8 a = *(const bf16x8*)&S.m1[row * 136 + ((t * 4 + quad) ^ rs) * 8];
                        acc0 = mfma16(a, bw2[t][0], acc0);
                        acc1 = mfma16(a, bw2[t][1], acc1);
                    }
                    #pragma unroll
                    for (int cc = 0; cc < 2; cc++) {
                        f32x4 acc = cc ? acc1 : acc0;
                        int col = (2 * w + cc) * 16 + m;
                        #pragma unroll
                        for (int rr = 0; rr < 4; rr++) {
                            int orow = mt * 16 + quad * 4 + rr;
                            S.msg[orow * 136 + col] = f2bf(fast_silu(acc[rr] + b2v[cc]));
                        }
                    }
                }
                __syncthreads();
                #pragma unroll
                for (int mt = 0; mt < 4; mt++) {
                    f32x4 acc0 = (f32x4){0,0,0,0}, acc1 = (f32x4){0,0,0,0};
                    #pragma unroll
                    for (int t = 0; t < 4; t++) {
                        bf16x8 a = *(const bf16x8*)&S.msg[(mt * 16 + m) * 136 + t * 32 + ksub];
                        acc0 = mfma16(a, bp1[t][0], acc0);
                        acc1 = mfma16(a, bp1[t][1], acc1);
                    }
                    float p4[4];
                    #pragma unroll
                    for (int rr = 0; rr < 4; rr++)
                        p4[rr] = fast_silu(acc0[rr] + pb1v[0]) * pw2v[0]
                               + fast_silu(acc1[rr] + pb1v[1]) * pw2v[1];
                    #pragma unroll
                    for (int mask = 1; mask < 16; mask <<= 1) {
                        #pragma unroll
                        for (int rr = 0; rr < 4; rr++) p4[rr] += __shfl_xor(p4[rr], mask);
                    }
                    if (m == 0) {
                        #pragma unroll
                        for (int rr = 0; rr < 4; rr++)
                            S.pcpart[w][mt * 16 + quad * 4 + rr] = p4[rr];
                    }
                }
                {
                    int half = tid >> 7, col = tid & 127;
                    int r0 = half * 32;
                    float a = 0.f;
                    int cur = S.rcvloc[r0];
                    for (int rr = r0; rr < r0 + 32; ++rr) {
                        int rc = S.rcvloc[rr];
                        if (rc != cur) {
                            atomicAdd(&p.agg[(size_t)cur * 128 + col], a);
                            a = 0.f; cur = rc;
                        }
                        a += bf2f(S.msg[rr * 136 + col]);
                    }
                    atomicAdd(&p.agg[(size_t)cur * 128 + col], a);
                }
                __syncthreads();
                if (tid < 192) {
                    int ee = tid / 3, c = tid - ee * 3;
                    float pc = S.pcpart[0][ee] + S.pcpart[1][ee] + S.pcpart[2][ee] + S.pcpart[3][ee];
                    float tr = S.diff[ee][c] * pc;
                    tr = fminf(fmaxf(tr, -100.f), 100.f);
                    atomicAdd(&p.posacc[S.sndloc[ee] * 3 + c], tr);
                }
            }
        } else if (ph == 7) {
            bf16x8 bw1[4][2], bw2[4][2];
            float b1v[2], b2v[2];
            #pragma unroll
            for (int cc = 0; cc < 2; cc++) {
                int col = (2 * w + cc) * 16 + m;
                #pragma unroll
                for (int t = 0; t < 4; t++) {
                    bw1[t][cc] = ld8(p.nW1T + col * 256 + 128 + t * 32 + ksub);
                    bw2[t][cc] = ld8(p.nW2T + col * 128 + t * 32 + ksub);
                }
                b1v[cc] = p.nb1[col];
                b2v[cc] = p.nb2[col];
            }
            for (int it = blockIdx.x; it < NTILE_N; it += gridDim.x) {
                const int base = it * 64;
                __syncthreads();
                #pragma unroll
                for (int mt = 0; mt < 4; mt++) {
                    int nm = base + mt * 16 + m;
                    if (nm >= NNODES) nm = NNODES - 1;
                    f32x4 acc0 = (f32x4){0,0,0,0}, acc1 = (f32x4){0,0,0,0};
                    #pragma unroll
                    for (int t = 0; t < 4; t++) {
                        const float* ap = p.agg + (size_t)nm * 128 + t * 32 + ksub;
                        f32x4 lo = *(const f32x4*)ap;
                        f32x4 hi = *(const f32x4*)(ap + 4);
                        bf16x8 a;
                        #pragma unroll
                        for (int j = 0; j < 4; j++) {
                            a[j]     = (short)f2bf(lo[j]);
                            a[4 + j] = (short)f2bf(hi[j]);
                        }
                        acc0 = mfma16(a, bw1[t][0], acc0);
                        acc1 = mfma16(a, bw1[t][1], acc1);
                    }
                    #pragma unroll
                    for (int cc = 0; cc < 2; cc++) {
                        f32x4 acc = cc ? acc1 : acc0;
                        int col = (2 * w + cc) * 16 + m;
                        #pragma unroll
                        for (int rr = 0; rr < 4; rr++) {
                            int row = mt * 16 + quad * 4 + rr;
                            int nrc = base + row; if (nrc >= NNODES) nrc = NNODES - 1;
                            float v = acc[rr] + bf2f(p.P[(size_t)nrc * 384 + 256 + col]) + b1v[cc];
                            U.nm1[row * 136 + col] = f2bf(fast_silu(v));
                        }
                    }
                }
                __syncthreads();
                #pragma unroll
                for (int mt = 0; mt < 4; mt++) {
                    f32x4 acc0 = (f32x4){0,0,0,0}, acc1 = (f32x4){0,0,0,0};
                    #pragma unroll
                    for (int t = 0; t < 4; t++) {
                        bf16x8 a = *(const bf16x8*)&U.nm1[(mt * 16 + m) * 136 + t * 32 + ksub];
                        acc0 = mfma16(a, bw2[t][0], acc0);
                        acc1 = mfma16(a, bw2[t][1], acc1);
                    }
                    #pragma unroll
                    for (int cc = 0; cc < 2; cc++) {
                        f32x4 acc = cc ? acc1 : acc0;
                        int col = (2 * w + cc) * 16 + m;
                        #pragma unroll
                        for (int rr = 0; rr < 4; rr++) {
                            int nr = base + mt * 16 + quad * 4 + rr;
                            if (nr < NNODES)
                                p.out[(size_t)nr * 128 + col] = acc[rr] + b2v[cc] + p.h[(size_t)nr * 128 + col];
                        }
                    }
                }
            }
            for (int i = gid; i < NNODES * 3; i += gsz)
                p.out[(size_t)NNODES * 128 + i] = p.pos[i] + p.posacc[i];
        }
        if (ph != phi) {
            __threadfence();
            cg::this_grid().sync();
        }
    }
}

extern "C" void kernel_launch(void* const* d_in, const int* in_sizes, int n_in,
                              void* d_out, int out_size, void* d_ws, size_t ws_size,
                              hipStream_t stream) {
    (void)in_sizes; (void)n_in; (void)out_size; (void)ws_size;
    MegaParams p;
    p.h   = (const float*)d_in[0];
    p.pos = (const float*)d_in[1];
    p.snd = (const int*)d_in[2];
    p.rcv = (const int*)d_in[3];
    p.eW1 = (const float*)d_in[4];
    p.eb1 = (const float*)d_in[5];
    p.eW2 = (const float*)d_in[6];
    p.eb2 = (const float*)d_in[7];
    p.nW1 = (const float*)d_in[8];
    p.nb1 = (const float*)d_in[9];
    p.nW2 = (const float*)d_in[10];
    p.nb2 = (const float*)d_in[11];
    p.pW1 = (const float*)d_in[12];
    p.pb1 = (const float*)d_in[13];
    p.pW2 = (const float*)d_in[14];
    p.out = (float*)d_out;

    p.agg    = (float*)d_ws;
    p.posacc = p.agg + (size_t)NNODES * 128;
    p.counts = (int*)(p.posacc + (size_t)NNODES * 3);
    p.excl   = p.counts + 50048;
    p.blkSum = p.excl + 50048;
    p.blkOff = p.blkSum + 256;
    p.perm   = p.blkOff + 256;
    p.P      = (u16*)(p.perm + NEDGES);
    p.eW1T   = p.P + (size_t)NNODES * 384;
    p.eW2T   = p.eW1T + 128 * 256;
    p.pW1T   = p.eW2T + 128 * 128;
    p.nW1T   = p.pW1T + 128 * 128;
    p.nW2T   = p.nW1T + 128 * 256;

    int dev = 0;
    hipGetDevice(&dev);
    int coop = 0, ncu = 0;
    hipDeviceGetAttribute(&coop, hipDeviceAttributeCooperativeLaunch, dev);
    hipDeviceGetAttribute(&ncu, hipDeviceAttributeMultiprocessorCount, dev);

    bool done = false;
    if (coop && ncu > 0) {
        int maxB = 0;
        hipError_t oe = hipOccupancyMaxActiveBlocksPerMultiprocessor(
            &maxB, (const void*)mega, 256, 0);
        if (oe == hipSuccess && maxB > 0) {
            int grid = maxB * ncu;
            if (grid > 1024) grid = 1024;
            int plo = 1, phi = 7;
            void* args[] = {(void*)&p, (void*)&plo, (void*)&phi};
            hipError_t le = hipLaunchCooperativeKernel((const void*)mega, dim3(grid),
                                                       dim3(256), args, 0, stream);
            done = (le == hipSuccess);
        }
    }
    if (!done) {
        static const int grids[8] = {0, 2048, 3904, 196, 1, 3125, 1024, 1024};
        for (int ph = 1; ph <= 7; ph++)
            mega<<<grids[ph], 256, 0, stream>>>(p, ph, ph);
    }
}